// Round 14
// baseline (149.630 us; speedup 1.0000x reference)
//
#include <hip/hip_runtime.h>

// CTC forward loss, MI355X — fwd/bwd split (bwd = verified fwd machinery in
// reversed state coords rho=200-s, reversed labels). R14 (schedule-only vs R13):
//  * FINL split: exchange READS issue right after the exchange writes (drain
//    under ISSUE/LOADR); reconcile COMPUTE runs after LOADR.
//  * WAITV fence relaxed to sched_barrier(0x7) (VALU may cross, DS/VMEM not).
// Records PRE-EXPONENTIATED (q=exp(lp-gmax), 104 f32/rec), per-b contiguous.
// LDS-staged records via global_load_lds + counted vmcnt; per-lane octave
// counters, left-only exponent inheritance.

#define TT 2000
#define BB 64
#define VV 128
#define LL 100
#define REC 104
#define REC_BASE 256
#define NEGF (-1e30f)
#define L2E 1.44269504f
#define LN2 0.69314718f

#define SLOTW 1088
#define NSLOT 4
#define EXCH_BASE (NSLOT * SLOTW)        // float offset of exchange region
#define WREG (NSLOT * SLOTW + 384)       // floats per wave's LDS region
#define SB_STATE (REC_BASE + BB * TT * REC)
#define AREA 336

__device__ __forceinline__ float wave_max64(float v) {
#pragma unroll
  for (int o = 32; o > 0; o >>= 1) v = fmaxf(v, __shfl_xor(v, o, 64));
  return v;
}
__device__ __forceinline__ float wave_sum64(float v) {
#pragma unroll
  for (int o = 32; o > 0; o >>= 1) v += __shfl_xor(v, o, 64);
  return v;
}

__global__ __launch_bounds__(256) void k_gather(const float* __restrict__ acts,
                                                const int* __restrict__ target,
                                                float* __restrict__ ws) {
  const int lane = threadIdx.x & 63;
  const int w = threadIdx.x >> 6;
  const int r = blockIdx.x * 4 + w;          // r = t*BB + b
  if (r >= TT * BB) return;
  const int b = r % BB;
  const int t = r / BB;
  const float* row = acts + (size_t)r * VV;
  float x0 = row[lane];
  float x1 = row[lane + 64];
  float m = wave_max64(fmaxf(x0, x1));
  float e = __builtin_exp2f((x0 - m) * L2E) + __builtin_exp2f((x1 - m) * L2E);
  float s = wave_sum64(e);
  float lse = m + __builtin_log2f(s) * LN2;
  const int* lab = target + b * LL;
  int c1 = lab[lane];
  int j2 = 64 + lane;
  int c2 = (j2 < LL) ? lab[j2] : 1;
  float y1lo = __shfl(x0, c1 & 63, 64);
  float y1hi = __shfl(x1, c1 & 63, 64);
  float y1 = (c1 < 64) ? y1lo : y1hi;
  float y2lo = __shfl(x0, c2 & 63, 64);
  float y2hi = __shfl(x1, c2 & 63, 64);
  float y2 = (c2 < 64) ? y2lo : y2hi;
  float g1 = y1 - lse;
  float g2 = (j2 < LL) ? (y2 - lse) : NEGF;
  float gb = __shfl(x0, 0, 64) - lse;
  float gm = wave_max64(fmaxf(fmaxf(g1, g2), gb));
  float q1 = __builtin_exp2f((g1 - gm) * L2E);
  float q2 = (j2 < LL) ? __builtin_exp2f((g2 - gm) * L2E) : 0.0f;
  float* rec = ws + REC_BASE + ((size_t)b * TT + t) * REC;
  rec[2 + lane] = q1;
  if (lane < 38) rec[66 + lane] = q2;
  if (lane == 0) { rec[0] = __builtin_exp2f((gb - gm) * L2E); rec[1] = gm; }
}

__device__ __forceinline__ void gl_lds16(const float* g, float* l) {
  __builtin_amdgcn_global_load_lds(
      (const __attribute__((address_space(1))) unsigned int*)g,
      (__attribute__((address_space(3))) unsigned int*)l, 16, 0, 0);
}
__device__ __forceinline__ void gl_lds4(const float* g, float* l) {
  __builtin_amdgcn_global_load_lds(
      (const __attribute__((address_space(1))) unsigned int*)g,
      (__attribute__((address_space(3))) unsigned int*)l, 4, 0, 0);
}
// vmcnt wait: DS/VMEM may not cross (staging-read ordering), VALU may (0x7).
#define WAITV(N) do { asm volatile("s_waitcnt vmcnt(" #N ")" ::: "memory");  \
                      __builtin_amdgcn_sched_barrier(0x7); } while (0)
#define BPER __builtin_amdgcn_ds_bpermute

// stage block bidx: 4 records at t = tA + TS*(4*bidx+k), k=0..3
#define ISSUE(bidx) do {                                                     \
  int bi_ = (bidx); bi_ = (bi_ < bcap) ? bi_ : bcap; if (bi_ < 0) bi_ = 0;   \
  float* sb_ = lds + (((unsigned)(bidx)) & 3u) * SLOTW;                      \
  const float* r0_ = recs_b + (size_t)(tA + TS * 4 * bi_) * REC;             \
  const float* q_ = r0_ + qbase;                                             \
  gl_lds16(q_,                 sb_);                                         \
  gl_lds16(q_ + TS * REC,      sb_ + 256);                                   \
  gl_lds16(q_ + TS * 2 * REC,  sb_ + 512);                                   \
  gl_lds16(q_ + TS * 3 * REC,  sb_ + 768);                                   \
  gl_lds4(r0_ + hoff,          sb_ + 1024);                                  \
} while (0)

#define DECLR(P) float4 P##q0, P##q1, P##q2, P##q3, P##h01, P##h23; float P##aY

// fwd: q = V; bwd: q = {V.w, V.z, V.y*cm, V.x*cm} (reversed labels; c masked l>=50)
#define LOADR(P, bidx) do {                                                  \
  const float* sb_ = lds + (((unsigned)(bidx)) & 3u) * SLOTW;                \
  float4 V0_ = *(const float4*)(sb_ + 4 * l);                                \
  float4 V1_ = *(const float4*)(sb_ + 256 + 4 * l);                          \
  float4 V2_ = *(const float4*)(sb_ + 512 + 4 * l);                          \
  float4 V3_ = *(const float4*)(sb_ + 768 + 4 * l);                          \
  if constexpr (DIR) {                                                       \
    P##q0 = (float4){V0_.w, V0_.z, V0_.y * cmask, V0_.x * cmask};            \
    P##q1 = (float4){V1_.w, V1_.z, V1_.y * cmask, V1_.x * cmask};            \
    P##q2 = (float4){V2_.w, V2_.z, V2_.y * cmask, V2_.x * cmask};            \
    P##q3 = (float4){V3_.w, V3_.z, V3_.y * cmask, V3_.x * cmask};            \
  } else { P##q0 = V0_; P##q1 = V1_; P##q2 = V2_; P##q3 = V3_; }             \
  P##h01 = *(const float4*)(sb_ + 1024);                                     \
  P##h23 = *(const float4*)(sb_ + 1028);                                     \
  P##aY = sb_[aoff];                                                         \
} while (0)

// top-down in-place update; NH = halo pairs updated (3/2/1/0)
#define STEP(qbv, gmv, cx, cy, bx, by, ay, NH) do {                          \
  const float qb_ = (qbv); msum += (gmv);                                    \
  o3 = __builtin_fmaf(cs_o3, o1, o3 + o2) * (cy);                            \
  o2 = (o2 + o1) * qb_;                                                      \
  o1 = __builtin_fmaf(cs_o1, h1, o1 + o0) * (cx);                            \
  o0 = (o0 + h1) * qb_;                                                      \
  if (NH >= 1) { h1 = __builtin_fmaf(cs_h1, h3, h1 + h2) * (by);             \
                 h2 = (h2 + h3) * qb_; }                                     \
  if (NH >= 2) { h3 = __builtin_fmaf(cs_h3, h5, h3 + h4) * (bx);             \
                 h4 = (h4 + h5) * qb_; }                                     \
  if (NH >= 3) { h5 = __builtin_fmaf(cs_h5, h7, h5 + h6) * (ay);             \
                 h6 = (h6 + h7) * qb_; }                                     \
} while (0)

// 4 steps + exchange WRITE
#define COMPA(P) do {                                                        \
  STEP(P##h01.x, P##h01.y, P##q0.z, P##q0.w, P##q0.x, P##q0.y, P##aY, 3);    \
  STEP(P##h01.z, P##h01.w, P##q1.z, P##q1.w, P##q1.x, P##q1.y, 0.f, 2);      \
  STEP(P##h23.x, P##h23.y, P##q2.z, P##q2.w, P##q2.x, P##q2.y, 0.f, 1);      \
  STEP(P##h23.z, P##h23.w, P##q3.z, P##q3.w, 0.f, 0.f, 0.f, 0);              \
  *(float4*)(exb + 4 * l) = (float4){o0, o1, o2, o3};                        \
  ((int*)exb)[256 + l] = offs;                                               \
} while (0)

// exchange READ: issue immediately after the writes (drains under ISSUE/LOADR)
#define FINL_RD() \
  asm volatile("" ::: "memory");  /* cross-lane RAW invisible to compiler */ \
  float4 L1_ = *(const float4*)(exb + 4 * ((l >= 1) ? (l - 1) : 0));         \
  float4 L2_ = *(const float4*)(exb + 4 * ((l >= 2) ? (l - 2) : 0));         \
  int ro1_ = ((const int*)exb)[256 + ((l >= 1) ? (l - 1) : 0)];              \
  int ro2_ = ((const int*)exb)[256 + ((l >= 2) ? (l - 2) : 0)]

// exchange reconcile COMPUTE (numerics identical to R13)
#define FINL_FX() do {                                                       \
  ro1_ = (l >= 1) ? ro1_ : -(1 << 29);                                       \
  ro2_ = (l >= 2) ? ro2_ : -(1 << 29);                                       \
  float m_ = fmaxf(fmaxf(o0, o1), fmaxf(o2, o3));                            \
  int eb_ = (int)((__float_as_uint(m_) >> 23) & 255u);                       \
  int t1_ = offs + (eb_ ? (eb_ - 127) : -126);                               \
  int mx_ = (ro1_ > ro2_) ? ro1_ : ro2_;                                     \
  int onew_ = (t1_ > mx_) ? t1_ : mx_;                                       \
  int ds_ = offs - onew_;  ds_ = (ds_ < -300) ? -300 : ds_;                  \
  int d1_ = ro1_ - onew_, d2_ = ro2_ - onew_;                                \
  d1_ = (d1_ < -300) ? -300 : d1_;                                           \
  d2_ = (d2_ < -300) ? -300 : d2_;                                           \
  o0 = ldexpf(o0, ds_); o1 = ldexpf(o1, ds_);                                \
  o2 = ldexpf(o2, ds_); o3 = ldexpf(o3, ds_);                                \
  h1 = ldexpf(L1_.w, d1_) * msk1;                                            \
  h2 = ldexpf(L1_.z, d1_) * msk2;                                            \
  h3 = ldexpf(L1_.y, d1_) * msk3;                                            \
  h4 = ldexpf(L1_.x, d1_) * msk4;                                            \
  h5 = ldexpf(L2_.w, d2_) * msk5;                                            \
  h6 = ldexpf(L2_.z, d2_) * msk6;                                            \
  h7 = ldexpf(L2_.y, d2_) * msk7;                                            \
  offs = onew_;                                                              \
} while (0)

template <int DIR>
__device__ __forceinline__ void run_chain(const int* __restrict__ target,
                                          const int* __restrict__ lablens,
                                          const float* __restrict__ recs_b,
                                          float* lds, int size, int b, int l,
                                          float* __restrict__ ws) {
  float* exb = lds + EXCH_BASE;
  const int mid = (size - 1) >> 1;
  const int sizeP = DIR ? (size - 1 - mid) : (mid + 1);
  const int* lab = target + b * LL;
  const int lc = (l < 50) ? l : 50;
  const int qbase = DIR ? (100 - 2 * lc) : (2 * lc);
  const int tA = DIR ? (size - 2) : 1;
  constexpr int TS = DIR ? -1 : 1;
  const int bcap = DIR ? ((size - 5) >> 2) : 498;
  const int hoff = (l < 8) ? (TS * (l >> 1) * REC + (l & 1)) : 0;
  const int aoff = (l >= 1) ? (4 * (l - 1) + (DIR ? 2 : 1)) : 0;
  const float cmask = (l < 50) ? 1.f : 0.f;
  const int idx1 = ((l + 63) & 63) << 2;
  const float msk1 = (4 * l - 1 >= 0) ? 1.f : 0.f;
  const float msk2 = (4 * l - 2 >= 0) ? 1.f : 0.f;
  const float msk3 = (4 * l - 3 >= 0) ? 1.f : 0.f;
  const float msk4 = (4 * l - 4 >= 0) ? 1.f : 0.f;
  const float msk5 = (4 * l - 5 >= 0) ? 1.f : 0.f;
  const float msk6 = (4 * l - 6 >= 0) ? 1.f : 0.f;
  const float msk7 = (4 * l - 7 >= 0) ? 1.f : 0.f;
  // skip masks: fwd from lab ascending; bwd from reversed labels lab'[j]=lab[99-j]
  int i0, i1, i2, i3, i4, i5;
  if constexpr (DIR == 0) { i0 = 2*l+1; i1 = 2*l; i2 = 2*l-1; i3 = 2*l-2; i4 = 2*l-3; i5 = 2*l-4; }
  else { i0 = 98-2*l; i1 = 99-2*l; i2 = 100-2*l; i3 = 101-2*l; i4 = 102-2*l; i5 = 103-2*l; }
#define CLM(x) ((x) < 0 ? 0 : ((x) > 99 ? 99 : (x)))
  const int La = lab[CLM(i0)], Lb_ = lab[CLM(i1)], Lc = lab[CLM(i2)];
  const int Ld = lab[CLM(i3)], Le = lab[CLM(i4)], Lf = lab[CLM(i5)];
  const float cs_o3 = (La != Lb_) ? 1.f : 0.f;
  const float cs_o1 = (Lb_ != Lc) ? 1.f : 0.f;
  const float cs_h1 = (Lc != Ld) ? 1.f : 0.f;
  const float cs_h3 = (Ld != Le) ? 1.f : 0.f;
  const float cs_h5 = (Le != Lf) ? 1.f : 0.f;
  // init
  float o0 = 0.f, o1 = 0.f, o2 = 0.f, o3 = 0.f;
  float h1 = 0.f, h2 = 0.f, h3 = 0.f, h4 = 0.f, h5 = 0.f, h6 = 0.f, h7 = 0.f;
  int offs = 0;
  float msum;
  if constexpr (DIR == 0) {
    msum = recs_b[1];
    if (l == 0) { o0 = recs_b[0]; o1 = recs_b[2]; }
    if (l == 1) { h3 = recs_b[2]; h4 = recs_b[0]; }
    if (l == 2) { h7 = recs_b[2]; }
  } else {
    const float* recL = recs_b + (size_t)(size - 1) * REC;
    msum = recL[1];
    const int Lbv = lablens[b];
    const int r0v = 200 - 2 * Lbv;   // rho of end state 2L; r0v+1 = rho of 2L-1
    auto gi = [&](int rho) -> float {
      if (rho != r0v && rho != r0v + 1) return 0.f;
      if ((rho & 1) == 0) return recL[0];
      return recL[2 + 99 - ((rho - 1) >> 1)];
    };
    o0 = gi(4*l); o1 = gi(4*l+1); o2 = gi(4*l+2); o3 = gi(4*l+3);
    h1 = gi(4*l-1); h2 = gi(4*l-2); h3 = gi(4*l-3); h4 = gi(4*l-4);
    h5 = gi(4*l-5); h6 = gi(4*l-6); h7 = gi(4*l-7);
  }

  const int nb = (sizeP - 1) >> 2;
  DECLR(A); DECLR(B);
  ISSUE(0); ISSUE(1); ISSUE(2);
  WAITV(10);
  LOADR(A, 0);
  int blk = 0;
  for (; blk + 2 <= nb; blk += 2) {
    { COMPA(A); FINL_RD(); ISSUE(blk + 3); WAITV(10); LOADR(B, blk + 1); FINL_FX(); }
    { COMPA(B); FINL_RD(); ISSUE(blk + 4); WAITV(10); LOADR(A, blk + 2); FINL_FX(); }
  }
  WAITV(0);
  if (blk < nb) { COMPA(A); FINL_RD(); FINL_FX(); }
  // tail (<=3 steps) + forward-only extra A-step
  {
    int rno1 = BPER(idx1, offs);
    int dtl = rno1 - offs;
    dtl = (dtl > 120) ? 120 : ((dtl < -300) ? -300 : dtl);
    for (int tau = 1 + 4 * nb; tau < sizeP; ++tau) {
      const float* rt = recs_b + (size_t)(DIR ? (size - 1 - tau) : tau) * REC;
      float2 hh = *(const float2*)rt;
      float cx, cy;
      if constexpr (DIR == 0) {
        float2 qc = *(const float2*)(rt + 2 + 2 * lc);
        cx = qc.x; cy = qc.y;
      } else {
        float2 qc = *(const float2*)(rt + qbase);
        cx = qc.y * cmask; cy = qc.x * cmask;
      }
      int rp = BPER(idx1, __float_as_int(o3));
      float p = ldexpf(__int_as_float(rp), dtl) * msk1;
      msum += hh.y;
      o3 = __builtin_fmaf(cs_o3, o1, o3 + o2) * cy;
      o2 = (o2 + o1) * hh.x;
      o1 = __builtin_fmaf(cs_o1, p, o1 + o0) * cx;
      o0 = (o0 + p) * hh.x;
    }
    if constexpr (DIR == 0) {   // alpha' = A * alpha_mid (absorbs leftover A^T)
      int rp = BPER(idx1, __float_as_int(o3));
      float p = ldexpf(__int_as_float(rp), dtl) * msk1;
      o3 = __builtin_fmaf(cs_o3, o1, o3 + o2);
      o2 = o2 + o1;
      o1 = __builtin_fmaf(cs_o1, p, o1 + o0);
      o0 = o0 + p;
    }
  }
  float* da = ws + SB_STATE + (size_t)(2 * b + DIR) * AREA;
  ((float4*)da)[l] = (float4){o0, o1, o2, o3};
  ((int*)da)[256 + l] = offs;
  if (l == 0) da[320] = msum;
}

// 128 threads = 2 independent waves per block: wave0 = fwd, wave1 = bwd (same b).
__global__ __launch_bounds__(128, 1) void k_alpha(const int* __restrict__ target,
                                                  const int* __restrict__ sizes,
                                                  const int* __restrict__ lablens,
                                                  float* __restrict__ ws) {
  __shared__ float ldsA[2 * WREG];
  const int b = blockIdx.x;
  const int dirw = threadIdx.x >> 6;
  const int l = threadIdx.x & 63;
  float* lds = ldsA + dirw * WREG;
  const int size = sizes[b];
  const float* recs_b = ws + REC_BASE + (size_t)b * TT * REC;
  if (dirw == 0) run_chain<0>(target, lablens, recs_b, lds, size, b, l, ws);
  else           run_chain<1>(target, lablens, recs_b, lds, size, b, l, ws);
}

__global__ __launch_bounds__(64) void k_comb(float* __restrict__ ws) {
  const int b = blockIdx.x;
  const int l = threadIdx.x;
  const float* fa = ws + SB_STATE + (size_t)(2 * b) * AREA;
  const float* ba = fa + AREA;
  float4 av = ((const float4*)fa)[l];
  int eF = ((const int*)fa)[256 + l];
  float msF = fa[320], msB = ba[320];
  float pr0, pr1, pr2, pr3; int ex0, ex1, ex2, ex3, sb0, sb1, sb2, sb3;
#define CMP(k, AV, PR, EX, SBE) do {                                         \
    int s_ = 4 * l + (k);                                                    \
    int rho_ = 200 - s_;                                                     \
    int rc_ = (rho_ < 0) ? 0 : rho_;                                         \
    float g_ = ba[rc_];                                                      \
    int eB_ = ((const int*)ba)[256 + (rc_ >> 2)];                            \
    float p_ = (AV) * g_;                                                    \
    bool ok_ = (rho_ >= 0) && (p_ > 0.f);                                    \
    int eb_ = (int)((__float_as_uint(p_) >> 23) & 255u);                     \
    SBE = eF + eB_;                                                          \
    EX = ok_ ? (SBE + (eb_ ? eb_ - 127 : -140)) : (int)0xC0000000;           \
    PR = ok_ ? p_ : 0.f;                                                     \
  } while (0)
  CMP(0, av.x, pr0, ex0, sb0);
  CMP(1, av.y, pr1, ex1, sb1);
  CMP(2, av.z, pr2, ex2, sb2);
  CMP(3, av.w, pr3, ex3, sb3);
  int Em = ex0 > ex1 ? ex0 : ex1;
  Em = ex2 > Em ? ex2 : Em;
  Em = ex3 > Em ? ex3 : Em;
#pragma unroll
  for (int o = 32; o > 0; o >>= 1) {
    int t = __shfl_xor(Em, o, 64);
    Em = (t > Em) ? t : Em;
  }
  float v = 0.f;
#define ACC(PR, SBE) do { if (PR > 0.f) {                                    \
    int sh_ = SBE - Em; sh_ = sh_ < -300 ? -300 : (sh_ > 300 ? 300 : sh_);   \
    v += ldexpf(PR, sh_); } } while (0)
  ACC(pr0, sb0); ACC(pr1, sb1); ACC(pr2, sb2); ACC(pr3, sb3);
  float S = wave_sum64(v);
  if (l == 0) ws[b] = msF + msB + LN2 * ((float)Em + __builtin_log2f(S));
}

__global__ __launch_bounds__(64) void k_final(const float* __restrict__ ws, float* __restrict__ out) {
  float v = (threadIdx.x < BB) ? ws[threadIdx.x] : 0.0f;
  v = wave_sum64(v);
  if (threadIdx.x == 0) out[0] = -v;
}

extern "C" void kernel_launch(void* const* d_in, const int* in_sizes, int n_in,
                              void* d_out, int out_size, void* d_ws, size_t ws_size,
                              hipStream_t stream) {
  const float* acts  = (const float*)d_in[0];
  const int* target  = (const int*)d_in[1];
  const int* sizes   = (const int*)d_in[2];
  const int* lablens = (const int*)d_in[3];
  float* ws  = (float*)d_ws;
  float* out = (float*)d_out;
  const int nrec = TT * BB;
  k_gather<<<dim3(nrec / 4), dim3(256), 0, stream>>>(acts, target, ws);
  k_alpha<<<dim3(BB), dim3(128), 0, stream>>>(target, sizes, lablens, ws);
  k_comb<<<dim3(BB), dim3(64), 0, stream>>>(ws);
  k_final<<<dim3(1), dim3(64), 0, stream>>>(ws, out);
}

// Round 15
// 131.213 us; speedup vs baseline: 1.1404x; 1.1404x over previous
//
#include <hip/hip_runtime.h>

// CTC forward loss, MI355X — fwd/bwd split (bwd = verified fwd machinery in
// reversed state coords rho=200-s, reversed labels). R15:
//  * record path is GLOBAL->REGISTER (plain loads, quad-buffered, no LDS, no asm
//    loads, no vmcnt management). FINL's "memory" fence pins each PREF's issue
//    point (loads can't sink across it), so prefetch distance ~3 iters holds.
//  * LDS is used ONLY for the 6-op/iter neighbor exchange (R13-proven).
// Records PRE-EXPONENTIATED (q=exp(lp-gmax), 104 f32/rec), per-b contiguous.

#define TT 2000
#define BB 64
#define VV 128
#define LL 100
#define REC 104
#define REC_BASE 256
#define NEGF (-1e30f)
#define L2E 1.44269504f
#define LN2 0.69314718f

#define SB_STATE (REC_BASE + BB * TT * REC)
#define AREA 336

__device__ __forceinline__ float wave_max64(float v) {
#pragma unroll
  for (int o = 32; o > 0; o >>= 1) v = fmaxf(v, __shfl_xor(v, o, 64));
  return v;
}
__device__ __forceinline__ float wave_sum64(float v) {
#pragma unroll
  for (int o = 32; o > 0; o >>= 1) v += __shfl_xor(v, o, 64);
  return v;
}

__global__ __launch_bounds__(256) void k_gather(const float* __restrict__ acts,
                                                const int* __restrict__ target,
                                                float* __restrict__ ws) {
  const int lane = threadIdx.x & 63;
  const int w = threadIdx.x >> 6;
  const int r = blockIdx.x * 4 + w;          // r = t*BB + b
  if (r >= TT * BB) return;
  const int b = r % BB;
  const int t = r / BB;
  const float* row = acts + (size_t)r * VV;
  float x0 = row[lane];
  float x1 = row[lane + 64];
  float m = wave_max64(fmaxf(x0, x1));
  float e = __builtin_exp2f((x0 - m) * L2E) + __builtin_exp2f((x1 - m) * L2E);
  float s = wave_sum64(e);
  float lse = m + __builtin_log2f(s) * LN2;
  const int* lab = target + b * LL;
  int c1 = lab[lane];
  int j2 = 64 + lane;
  int c2 = (j2 < LL) ? lab[j2] : 1;
  float y1lo = __shfl(x0, c1 & 63, 64);
  float y1hi = __shfl(x1, c1 & 63, 64);
  float y1 = (c1 < 64) ? y1lo : y1hi;
  float y2lo = __shfl(x0, c2 & 63, 64);
  float y2hi = __shfl(x1, c2 & 63, 64);
  float y2 = (c2 < 64) ? y2lo : y2hi;
  float g1 = y1 - lse;
  float g2 = (j2 < LL) ? (y2 - lse) : NEGF;
  float gb = __shfl(x0, 0, 64) - lse;
  float gm = wave_max64(fmaxf(fmaxf(g1, g2), gb));
  float q1 = __builtin_exp2f((g1 - gm) * L2E);
  float q2 = (j2 < LL) ? __builtin_exp2f((g2 - gm) * L2E) : 0.0f;
  float* rec = ws + REC_BASE + ((size_t)b * TT + t) * REC;
  rec[2 + lane] = q1;
  if (lane < 38) rec[66 + lane] = q2;
  if (lane == 0) { rec[0] = __builtin_exp2f((gb - gm) * L2E); rec[1] = gm; }
}

#define BPER __builtin_amdgcn_ds_bpermute

// per-buffer registers: 4 steps x {h(2), q(4 canonical: bx,by,cx,cy)} + aY
#define DECLR(P) float2 P##h0, P##h1, P##h2, P##h3; \
                 float4 P##q0, P##q1, P##q2, P##q3; float P##aY

// global->reg prefetch of one 4-step block (13 plain loads, DIR-canonicalized)
#define PREF(P, bidx) do {                                                   \
  int bi_ = (bidx); bi_ = (bi_ < bcap) ? bi_ : bcap; if (bi_ < 0) bi_ = 0;   \
  const float* r0_ = recs_b + (size_t)(tA + TS * 4 * bi_) * REC;             \
  P##h0 = *(const float2*)(r0_);                                             \
  P##h1 = *(const float2*)(r0_ + TS * REC);                                  \
  P##h2 = *(const float2*)(r0_ + TS * 2 * REC);                              \
  P##h3 = *(const float2*)(r0_ + TS * 3 * REC);                              \
  float2 lo0_ = *(const float2*)(r0_ + vofs);                                \
  float2 hi0_ = *(const float2*)(r0_ + vofs + 2);                            \
  float2 lo1_ = *(const float2*)(r0_ + TS * REC + vofs);                     \
  float2 hi1_ = *(const float2*)(r0_ + TS * REC + vofs + 2);                 \
  float2 lo2_ = *(const float2*)(r0_ + TS * 2 * REC + vofs);                 \
  float2 hi2_ = *(const float2*)(r0_ + TS * 2 * REC + vofs + 2);             \
  float2 lo3_ = *(const float2*)(r0_ + TS * 3 * REC + vofs);                 \
  float2 hi3_ = *(const float2*)(r0_ + TS * 3 * REC + vofs + 2);             \
  P##aY = r0_[ayofs];                                                        \
  if constexpr (DIR) {                                                       \
    P##q0 = (float4){hi0_.y, hi0_.x, lo0_.y * cmask, lo0_.x * cmask};        \
    P##q1 = (float4){hi1_.y, hi1_.x, lo1_.y * cmask, lo1_.x * cmask};        \
    P##q2 = (float4){hi2_.y, hi2_.x, lo2_.y * cmask, lo2_.x * cmask};        \
    P##q3 = (float4){hi3_.y, hi3_.x, lo3_.y * cmask, lo3_.x * cmask};        \
  } else {                                                                   \
    P##q0 = (float4){lo0_.x, lo0_.y, hi0_.x, hi0_.y};                        \
    P##q1 = (float4){lo1_.x, lo1_.y, hi1_.x, hi1_.y};                        \
    P##q2 = (float4){lo2_.x, lo2_.y, hi2_.x, hi2_.y};                        \
    P##q3 = (float4){lo3_.x, lo3_.y, hi3_.x, hi3_.y};                        \
  }                                                                          \
} while (0)

// top-down in-place update; NH = halo pairs updated (3/2/1/0)
#define STEP(qbv, gmv, cx, cy, bx, by, ay, NH) do {                          \
  const float qb_ = (qbv); msum += (gmv);                                    \
  o3 = __builtin_fmaf(cs_o3, o1, o3 + o2) * (cy);                            \
  o2 = (o2 + o1) * qb_;                                                      \
  o1 = __builtin_fmaf(cs_o1, h1, o1 + o0) * (cx);                            \
  o0 = (o0 + h1) * qb_;                                                      \
  if (NH >= 1) { h1 = __builtin_fmaf(cs_h1, h3, h1 + h2) * (by);             \
                 h2 = (h2 + h3) * qb_; }                                     \
  if (NH >= 2) { h3 = __builtin_fmaf(cs_h3, h5, h3 + h4) * (bx);             \
                 h4 = (h4 + h5) * qb_; }                                     \
  if (NH >= 3) { h5 = __builtin_fmaf(cs_h5, h7, h5 + h6) * (ay);             \
                 h6 = (h6 + h7) * qb_; }                                     \
} while (0)

// 4 steps + exchange WRITE
#define COMPA(P) do {                                                        \
  STEP(P##h0.x, P##h0.y, P##q0.z, P##q0.w, P##q0.x, P##q0.y, P##aY, 3);      \
  STEP(P##h1.x, P##h1.y, P##q1.z, P##q1.w, P##q1.x, P##q1.y, 0.f, 2);        \
  STEP(P##h2.x, P##h2.y, P##q2.z, P##q2.w, P##q2.x, P##q2.y, 0.f, 1);        \
  STEP(P##h3.x, P##h3.y, P##q3.z, P##q3.w, 0.f, 0.f, 0.f, 0);                \
  *(float4*)(exb + 4 * l) = (float4){o0, o1, o2, o3};                        \
  ((int*)exb)[256 + l] = offs;                                               \
} while (0)

// exchange READ + reconcile (numerics identical to R13). The "memory" fence
// also pins PREF's loads to their program-order issue slot each iteration.
#define FINL() do {                                                          \
  asm volatile("" ::: "memory");                                             \
  float4 L1_ = *(const float4*)(exb + 4 * ((l >= 1) ? (l - 1) : 0));         \
  float4 L2_ = *(const float4*)(exb + 4 * ((l >= 2) ? (l - 2) : 0));         \
  int ro1_ = ((const int*)exb)[256 + ((l >= 1) ? (l - 1) : 0)];              \
  int ro2_ = ((const int*)exb)[256 + ((l >= 2) ? (l - 2) : 0)];              \
  ro1_ = (l >= 1) ? ro1_ : -(1 << 29);                                       \
  ro2_ = (l >= 2) ? ro2_ : -(1 << 29);                                       \
  float m_ = fmaxf(fmaxf(o0, o1), fmaxf(o2, o3));                            \
  int eb_ = (int)((__float_as_uint(m_) >> 23) & 255u);                       \
  int t1_ = offs + (eb_ ? (eb_ - 127) : -126);                               \
  int mx_ = (ro1_ > ro2_) ? ro1_ : ro2_;                                     \
  int onew_ = (t1_ > mx_) ? t1_ : mx_;                                       \
  int ds_ = offs - onew_;  ds_ = (ds_ < -300) ? -300 : ds_;                  \
  int d1_ = ro1_ - onew_, d2_ = ro2_ - onew_;                                \
  d1_ = (d1_ < -300) ? -300 : d1_;                                           \
  d2_ = (d2_ < -300) ? -300 : d2_;                                           \
  o0 = ldexpf(o0, ds_); o1 = ldexpf(o1, ds_);                                \
  o2 = ldexpf(o2, ds_); o3 = ldexpf(o3, ds_);                                \
  h1 = ldexpf(L1_.w, d1_) * msk1;                                            \
  h2 = ldexpf(L1_.z, d1_) * msk2;                                            \
  h3 = ldexpf(L1_.y, d1_) * msk3;                                            \
  h4 = ldexpf(L1_.x, d1_) * msk4;                                            \
  h5 = ldexpf(L2_.w, d2_) * msk5;                                            \
  h6 = ldexpf(L2_.z, d2_) * msk6;                                            \
  h7 = ldexpf(L2_.y, d2_) * msk7;                                            \
  offs = onew_;                                                              \
} while (0)

template <int DIR>
__device__ __forceinline__ void run_chain(const int* __restrict__ target,
                                          const int* __restrict__ lablens,
                                          const float* __restrict__ recs_b,
                                          float* exb, int size, int b, int l,
                                          float* __restrict__ ws) {
  const int mid = (size - 1) >> 1;
  const int sizeP = DIR ? (size - 1 - mid) : (mid + 1);
  const int* lab = target + b * LL;
  const int lc = (l < 50) ? l : 50;
  const int vofs = DIR ? (100 - 2 * lc) : (2 * lc);
  const int tA = DIR ? (size - 2) : 1;
  constexpr int TS = DIR ? -1 : 1;
  const int bcap = DIR ? ((size - 5) >> 2) : 498;
  int ay_ = DIR ? (104 - 2 * l) : (2 * l - 1);
  ay_ = (ay_ < 0) ? 0 : ((ay_ > 103) ? 103 : ay_);
  const int ayofs = ay_;
  const float cmask = (l < 50) ? 1.f : 0.f;
  const int idx1 = ((l + 63) & 63) << 2;
  const float msk1 = (4 * l - 1 >= 0) ? 1.f : 0.f;
  const float msk2 = (4 * l - 2 >= 0) ? 1.f : 0.f;
  const float msk3 = (4 * l - 3 >= 0) ? 1.f : 0.f;
  const float msk4 = (4 * l - 4 >= 0) ? 1.f : 0.f;
  const float msk5 = (4 * l - 5 >= 0) ? 1.f : 0.f;
  const float msk6 = (4 * l - 6 >= 0) ? 1.f : 0.f;
  const float msk7 = (4 * l - 7 >= 0) ? 1.f : 0.f;
  // skip masks: fwd from lab ascending; bwd from reversed labels lab'[j]=lab[99-j]
  int i0, i1, i2, i3, i4, i5;
  if constexpr (DIR == 0) { i0 = 2*l+1; i1 = 2*l; i2 = 2*l-1; i3 = 2*l-2; i4 = 2*l-3; i5 = 2*l-4; }
  else { i0 = 98-2*l; i1 = 99-2*l; i2 = 100-2*l; i3 = 101-2*l; i4 = 102-2*l; i5 = 103-2*l; }
#define CLM(x) ((x) < 0 ? 0 : ((x) > 99 ? 99 : (x)))
  const int La = lab[CLM(i0)], Lb_ = lab[CLM(i1)], Lc = lab[CLM(i2)];
  const int Ld = lab[CLM(i3)], Le = lab[CLM(i4)], Lf = lab[CLM(i5)];
  const float cs_o3 = (La != Lb_) ? 1.f : 0.f;
  const float cs_o1 = (Lb_ != Lc) ? 1.f : 0.f;
  const float cs_h1 = (Lc != Ld) ? 1.f : 0.f;
  const float cs_h3 = (Ld != Le) ? 1.f : 0.f;
  const float cs_h5 = (Le != Lf) ? 1.f : 0.f;
  // init
  float o0 = 0.f, o1 = 0.f, o2 = 0.f, o3 = 0.f;
  float h1 = 0.f, h2 = 0.f, h3 = 0.f, h4 = 0.f, h5 = 0.f, h6 = 0.f, h7 = 0.f;
  int offs = 0;
  float msum;
  if constexpr (DIR == 0) {
    msum = recs_b[1];
    if (l == 0) { o0 = recs_b[0]; o1 = recs_b[2]; }
    if (l == 1) { h3 = recs_b[2]; h4 = recs_b[0]; }
    if (l == 2) { h7 = recs_b[2]; }
  } else {
    const float* recL = recs_b + (size_t)(size - 1) * REC;
    msum = recL[1];
    const int Lbv = lablens[b];
    const int r0v = 200 - 2 * Lbv;   // rho of end state 2L; r0v+1 = rho of 2L-1
    auto gi = [&](int rho) -> float {
      if (rho != r0v && rho != r0v + 1) return 0.f;
      if ((rho & 1) == 0) return recL[0];
      return recL[2 + 99 - ((rho - 1) >> 1)];
    };
    o0 = gi(4*l); o1 = gi(4*l+1); o2 = gi(4*l+2); o3 = gi(4*l+3);
    h1 = gi(4*l-1); h2 = gi(4*l-2); h3 = gi(4*l-3); h4 = gi(4*l-4);
    h5 = gi(4*l-5); h6 = gi(4*l-6); h7 = gi(4*l-7);
  }

  const int nb = (sizeP - 1) >> 2;
  DECLR(A); DECLR(B); DECLR(C); DECLR(D);
  PREF(A, 0); PREF(B, 1); PREF(C, 2);
  int blk = 0;
  for (; blk + 4 <= nb; blk += 4) {
    COMPA(A); PREF(D, blk + 3); FINL();
    COMPA(B); PREF(A, blk + 4); FINL();
    COMPA(C); PREF(B, blk + 5); FINL();
    COMPA(D); PREF(C, blk + 6); FINL();
  }
  if (nb - blk >= 1) { COMPA(A); FINL(); }
  if (nb - blk >= 2) { COMPA(B); FINL(); }
  if (nb - blk >= 3) { COMPA(C); FINL(); }
  // tail (<=3 steps) + forward-only extra A-step
  {
    int rno1 = BPER(idx1, offs);
    int dtl = rno1 - offs;
    dtl = (dtl > 120) ? 120 : ((dtl < -300) ? -300 : dtl);
    for (int tau = 1 + 4 * nb; tau < sizeP; ++tau) {
      const float* rt = recs_b + (size_t)(DIR ? (size - 1 - tau) : tau) * REC;
      float2 hh = *(const float2*)rt;
      float cx, cy;
      if constexpr (DIR == 0) {
        float2 qc = *(const float2*)(rt + 2 + 2 * lc);
        cx = qc.x; cy = qc.y;
      } else {
        float2 qc = *(const float2*)(rt + vofs + 2);
        cx = qc.y * cmask; cy = qc.x * cmask;
      }
      int rp = BPER(idx1, __float_as_int(o3));
      float p = ldexpf(__int_as_float(rp), dtl) * msk1;
      msum += hh.y;
      o3 = __builtin_fmaf(cs_o3, o1, o3 + o2) * cy;
      o2 = (o2 + o1) * hh.x;
      o1 = __builtin_fmaf(cs_o1, p, o1 + o0) * cx;
      o0 = (o0 + p) * hh.x;
    }
    if constexpr (DIR == 0) {   // alpha' = A * alpha_mid (absorbs leftover A^T)
      int rp = BPER(idx1, __float_as_int(o3));
      float p = ldexpf(__int_as_float(rp), dtl) * msk1;
      o3 = __builtin_fmaf(cs_o3, o1, o3 + o2);
      o2 = o2 + o1;
      o1 = __builtin_fmaf(cs_o1, p, o1 + o0);
      o0 = o0 + p;
    }
  }
  float* da = ws + SB_STATE + (size_t)(2 * b + DIR) * AREA;
  ((float4*)da)[l] = (float4){o0, o1, o2, o3};
  ((int*)da)[256 + l] = offs;
  if (l == 0) da[320] = msum;
}

// 128 threads = 2 independent waves per block: wave0 = fwd, wave1 = bwd (same b).
__global__ __launch_bounds__(128, 1) void k_alpha(const int* __restrict__ target,
                                                  const int* __restrict__ sizes,
                                                  const int* __restrict__ lablens,
                                                  float* __restrict__ ws) {
  __shared__ float ldsA[2 * 384];
  const int b = blockIdx.x;
  const int dirw = threadIdx.x >> 6;
  const int l = threadIdx.x & 63;
  float* exb = ldsA + dirw * 384;
  const int size = sizes[b];
  const float* recs_b = ws + REC_BASE + (size_t)b * TT * REC;
  if (dirw == 0) run_chain<0>(target, lablens, recs_b, exb, size, b, l, ws);
  else           run_chain<1>(target, lablens, recs_b, exb, size, b, l, ws);
}

__global__ __launch_bounds__(64) void k_comb(float* __restrict__ ws) {
  const int b = blockIdx.x;
  const int l = threadIdx.x;
  const float* fa = ws + SB_STATE + (size_t)(2 * b) * AREA;
  const float* ba = fa + AREA;
  float4 av = ((const float4*)fa)[l];
  int eF = ((const int*)fa)[256 + l];
  float msF = fa[320], msB = ba[320];
  float pr0, pr1, pr2, pr3; int ex0, ex1, ex2, ex3, sb0, sb1, sb2, sb3;
#define CMP(k, AV, PR, EX, SBE) do {                                         \
    int s_ = 4 * l + (k);                                                    \
    int rho_ = 200 - s_;                                                     \
    int rc_ = (rho_ < 0) ? 0 : rho_;                                         \
    float g_ = ba[rc_];                                                      \
    int eB_ = ((const int*)ba)[256 + (rc_ >> 2)];                            \
    float p_ = (AV) * g_;                                                    \
    bool ok_ = (rho_ >= 0) && (p_ > 0.f);                                    \
    int eb_ = (int)((__float_as_uint(p_) >> 23) & 255u);                     \
    SBE = eF + eB_;                                                          \
    EX = ok_ ? (SBE + (eb_ ? eb_ - 127 : -140)) : (int)0xC0000000;           \
    PR = ok_ ? p_ : 0.f;                                                     \
  } while (0)
  CMP(0, av.x, pr0, ex0, sb0);
  CMP(1, av.y, pr1, ex1, sb1);
  CMP(2, av.z, pr2, ex2, sb2);
  CMP(3, av.w, pr3, ex3, sb3);
  int Em = ex0 > ex1 ? ex0 : ex1;
  Em = ex2 > Em ? ex2 : Em;
  Em = ex3 > Em ? ex3 : Em;
#pragma unroll
  for (int o = 32; o > 0; o >>= 1) {
    int t = __shfl_xor(Em, o, 64);
    Em = (t > Em) ? t : Em;
  }
  float v = 0.f;
#define ACC(PR, SBE) do { if (PR > 0.f) {                                    \
    int sh_ = SBE - Em; sh_ = sh_ < -300 ? -300 : (sh_ > 300 ? 300 : sh_);   \
    v += ldexpf(PR, sh_); } } while (0)
  ACC(pr0, sb0); ACC(pr1, sb1); ACC(pr2, sb2); ACC(pr3, sb3);
  float S = wave_sum64(v);
  if (l == 0) ws[b] = msF + msB + LN2 * ((float)Em + __builtin_log2f(S));
}

__global__ __launch_bounds__(64) void k_final(const float* __restrict__ ws, float* __restrict__ out) {
  float v = (threadIdx.x < BB) ? ws[threadIdx.x] : 0.0f;
  v = wave_sum64(v);
  if (threadIdx.x == 0) out[0] = -v;
}

extern "C" void kernel_launch(void* const* d_in, const int* in_sizes, int n_in,
                              void* d_out, int out_size, void* d_ws, size_t ws_size,
                              hipStream_t stream) {
  const float* acts  = (const float*)d_in[0];
  const int* target  = (const int*)d_in[1];
  const int* sizes   = (const int*)d_in[2];
  const int* lablens = (const int*)d_in[3];
  float* ws  = (float*)d_ws;
  float* out = (float*)d_out;
  const int nrec = TT * BB;
  k_gather<<<dim3(nrec / 4), dim3(256), 0, stream>>>(acts, target, ws);
  k_alpha<<<dim3(BB), dim3(128), 0, stream>>>(target, sizes, lablens, ws);
  k_comb<<<dim3(BB), dim3(64), 0, stream>>>(ws);
  k_final<<<dim3(1), dim3(64), 0, stream>>>(ws, out);
}

// Round 16
// 124.467 us; speedup vs baseline: 1.2022x; 1.0542x over previous
//
#include <hip/hip_runtime.h>

// CTC forward loss, MI355X — fwd/bwd split (bwd = verified fwd machinery in
// reversed state coords rho=200-s, reversed labels). R16:
//  * records BF16-PACKED: [0]=q_blank f32, [1]=gmax f32, [2..51]=u32 pairs
//    {bf16 q[2j], bf16 q[2j+1]}, [52]=0 pad. 56 floats/rec (was 104).
//    Buffer regs 26->17; TRIPLE-buffered global->reg prefetch now fully fits
//    in VGPRs (R15: VGPR=108 < needed -> compiler sank loads -> ~400cyc/iter
//    exposed latency). Unpack = u<<16 shifts, off the stall path.
//  * LDS only for the 6-op/iter neighbor exchange (R13-proven).

#define TT 2000
#define BB 64
#define VV 128
#define LL 100
#define RECW 56
#define REC_BASE 256
#define NEGF (-1e30f)
#define L2E 1.44269504f
#define LN2 0.69314718f

#define SB_STATE (REC_BASE + BB * TT * RECW)
#define AREA 336

__device__ __forceinline__ float wave_max64(float v) {
#pragma unroll
  for (int o = 32; o > 0; o >>= 1) v = fmaxf(v, __shfl_xor(v, o, 64));
  return v;
}
__device__ __forceinline__ float wave_sum64(float v) {
#pragma unroll
  for (int o = 32; o > 0; o >>= 1) v += __shfl_xor(v, o, 64);
  return v;
}
__device__ __forceinline__ float blo(unsigned u) { return __uint_as_float(u << 16); }
__device__ __forceinline__ float bhi(unsigned u) { return __uint_as_float(u & 0xFFFF0000u); }
__device__ __forceinline__ unsigned b16(float x) {
  unsigned b = __float_as_uint(x);
  return (b + 0x7FFFu + ((b >> 16) & 1u)) >> 16;   // RNE
}

__global__ __launch_bounds__(256) void k_gather(const float* __restrict__ acts,
                                                const int* __restrict__ target,
                                                float* __restrict__ ws) {
  const int lane = threadIdx.x & 63;
  const int w = threadIdx.x >> 6;
  const int r = blockIdx.x * 4 + w;          // r = t*BB + b
  if (r >= TT * BB) return;
  const int b = r % BB;
  const int t = r / BB;
  const float* row = acts + (size_t)r * VV;
  float x0 = row[lane];
  float x1 = row[lane + 64];
  float m = wave_max64(fmaxf(x0, x1));
  float e = __builtin_exp2f((x0 - m) * L2E) + __builtin_exp2f((x1 - m) * L2E);
  float s = wave_sum64(e);
  float lse = m + __builtin_log2f(s) * LN2;
  const int* lab = target + b * LL;
  const int j = lane;
  int ilo = (2 * j < 100) ? 2 * j : 99;
  int ihi = (2 * j + 1 < 100) ? 2 * j + 1 : 99;
  int cl = lab[ilo], ch = lab[ihi];
  float ya = __shfl(x0, cl & 63, 64), yb = __shfl(x1, cl & 63, 64);
  float ylo = (cl < 64) ? ya : yb;
  float yc = __shfl(x0, ch & 63, 64), yd = __shfl(x1, ch & 63, 64);
  float yhi = (ch < 64) ? yc : yd;
  float glo = (j < 50) ? (ylo - lse) : NEGF;
  float ghi = (j < 50) ? (yhi - lse) : NEGF;
  float gb = __shfl(x0, 0, 64) - lse;
  float gm = wave_max64(fmaxf(fmaxf(glo, ghi), gb));
  float qlo = __builtin_exp2f((glo - gm) * L2E);
  float qhi = __builtin_exp2f((ghi - gm) * L2E);
  unsigned u = b16(qlo) | (b16(qhi) << 16);
  unsigned* rec = (unsigned*)(ws + REC_BASE + ((size_t)b * TT + t) * RECW);
  if (j < 50) rec[2 + j] = u;
  if (j == 50) rec[52] = 0u;
  if (j == 0) {
    ((float*)rec)[0] = __builtin_exp2f((gb - gm) * L2E);
    ((float*)rec)[1] = gm;
  }
}

#define BPER __builtin_amdgcn_ds_bpermute
#define CL50(x) ((x) < 0 ? 0 : ((x) > 50 ? 50 : (x)))

// per-buffer: 4x h(float2) + 8x packed q + 1x packed aY = 17 regs
#define DECLR(P) float2 P##h0, P##h1, P##h2, P##h3; \
                 unsigned P##b0, P##b1, P##b2, P##b3, P##c0, P##c1, P##c2, P##c3, P##uA

// global->reg prefetch of one 4-step block (13 plain loads)
#define PREF(P, bidx) do {                                                   \
  int bi_ = (bidx); bi_ = (bi_ < bcap) ? bi_ : bcap; if (bi_ < 0) bi_ = 0;   \
  const float* r0_ = recs_b + (size_t)(tA + TS * 4 * bi_) * RECW;            \
  P##h0 = *(const float2*)(r0_);                                             \
  P##h1 = *(const float2*)(r0_ + TS * RECW);                                 \
  P##h2 = *(const float2*)(r0_ + TS * 2 * RECW);                             \
  P##h3 = *(const float2*)(r0_ + TS * 3 * RECW);                             \
  P##b0 = ((const unsigned*)r0_)[pbofs];                                     \
  P##c0 = ((const unsigned*)r0_)[pcofs];                                     \
  P##b1 = ((const unsigned*)(r0_ + TS * RECW))[pbofs];                       \
  P##c1 = ((const unsigned*)(r0_ + TS * RECW))[pcofs];                       \
  P##b2 = ((const unsigned*)(r0_ + TS * 2 * RECW))[pbofs];                   \
  P##c2 = ((const unsigned*)(r0_ + TS * 2 * RECW))[pcofs];                   \
  P##b3 = ((const unsigned*)(r0_ + TS * 3 * RECW))[pbofs];                   \
  P##c3 = ((const unsigned*)(r0_ + TS * 3 * RECW))[pcofs];                   \
  P##uA = ((const unsigned*)r0_)[payofs];                                    \
} while (0)

// top-down in-place update; NH = halo pairs updated (3/2/1/0)
#define STEP(qbv, gmv, cx, cy, bx, by, ay, NH) do {                          \
  const float qb_ = (qbv); msum += (gmv);                                    \
  o3 = __builtin_fmaf(cs_o3, o1, o3 + o2) * (cy);                            \
  o2 = (o2 + o1) * qb_;                                                      \
  o1 = __builtin_fmaf(cs_o1, h1, o1 + o0) * (cx);                            \
  o0 = (o0 + h1) * qb_;                                                      \
  if (NH >= 1) { h1 = __builtin_fmaf(cs_h1, h3, h1 + h2) * (by);             \
                 h2 = (h2 + h3) * qb_; }                                     \
  if (NH >= 2) { h3 = __builtin_fmaf(cs_h3, h5, h3 + h4) * (bx);             \
                 h4 = (h4 + h5) * qb_; }                                     \
  if (NH >= 3) { h5 = __builtin_fmaf(cs_h5, h7, h5 + h6) * (ay);             \
                 h6 = (h6 + h7) * qb_; }                                     \
} while (0)

// unpack to canonical (bx,by,cx,cy) — same operand mapping as R15, verified
#define UQ(P, K, QV) float4 QV; do {                                         \
  if constexpr (DIR) {                                                       \
    QV = (float4){bhi(P##b##K), blo(P##b##K),                                \
                  bhi(P##c##K) * cmask, blo(P##c##K) * cmask};               \
  } else {                                                                   \
    QV = (float4){blo(P##b##K), bhi(P##b##K), blo(P##c##K), bhi(P##c##K)};   \
  }                                                                          \
} while (0)

// 4 steps + exchange WRITE
#define COMPA(P) do {                                                        \
  UQ(P, 0, q0_); UQ(P, 1, q1_); UQ(P, 2, q2_); UQ(P, 3, q3_);                \
  float aYv = DIR ? blo(P##uA) : bhi(P##uA);                                 \
  STEP(P##h0.x, P##h0.y, q0_.z, q0_.w, q0_.x, q0_.y, aYv, 3);                \
  STEP(P##h1.x, P##h1.y, q1_.z, q1_.w, q1_.x, q1_.y, 0.f, 2);                \
  STEP(P##h2.x, P##h2.y, q2_.z, q2_.w, q2_.x, q2_.y, 0.f, 1);                \
  STEP(P##h3.x, P##h3.y, q3_.z, q3_.w, 0.f, 0.f, 0.f, 0);                    \
  *(float4*)(exb + 4 * l) = (float4){o0, o1, o2, o3};                        \
  ((int*)exb)[256 + l] = offs;                                               \
} while (0)

// exchange READ + reconcile (numerics identical to R13/R15)
#define FINL() do {                                                          \
  asm volatile("" ::: "memory");                                             \
  float4 L1_ = *(const float4*)(exb + 4 * ((l >= 1) ? (l - 1) : 0));         \
  float4 L2_ = *(const float4*)(exb + 4 * ((l >= 2) ? (l - 2) : 0));         \
  int ro1_ = ((const int*)exb)[256 + ((l >= 1) ? (l - 1) : 0)];              \
  int ro2_ = ((const int*)exb)[256 + ((l >= 2) ? (l - 2) : 0)];              \
  ro1_ = (l >= 1) ? ro1_ : -(1 << 29);                                       \
  ro2_ = (l >= 2) ? ro2_ : -(1 << 29);                                       \
  float m_ = fmaxf(fmaxf(o0, o1), fmaxf(o2, o3));                            \
  int eb_ = (int)((__float_as_uint(m_) >> 23) & 255u);                       \
  int t1_ = offs + (eb_ ? (eb_ - 127) : -126);                               \
  int mx_ = (ro1_ > ro2_) ? ro1_ : ro2_;                                     \
  int onew_ = (t1_ > mx_) ? t1_ : mx_;                                       \
  int ds_ = offs - onew_;  ds_ = (ds_ < -300) ? -300 : ds_;                  \
  int d1_ = ro1_ - onew_, d2_ = ro2_ - onew_;                                \
  d1_ = (d1_ < -300) ? -300 : d1_;                                           \
  d2_ = (d2_ < -300) ? -300 : d2_;                                           \
  o0 = ldexpf(o0, ds_); o1 = ldexpf(o1, ds_);                                \
  o2 = ldexpf(o2, ds_); o3 = ldexpf(o3, ds_);                                \
  h1 = ldexpf(L1_.w, d1_) * msk1;                                            \
  h2 = ldexpf(L1_.z, d1_) * msk2;                                            \
  h3 = ldexpf(L1_.y, d1_) * msk3;                                            \
  h4 = ldexpf(L1_.x, d1_) * msk4;                                            \
  h5 = ldexpf(L2_.w, d2_) * msk5;                                            \
  h6 = ldexpf(L2_.z, d2_) * msk6;                                            \
  h7 = ldexpf(L2_.y, d2_) * msk7;                                            \
  offs = onew_;                                                              \
} while (0)

template <int DIR>
__device__ __forceinline__ void run_chain(const int* __restrict__ target,
                                          const int* __restrict__ lablens,
                                          const float* __restrict__ recs_b,
                                          float* exb, int size, int b, int l,
                                          float* __restrict__ ws) {
  const int mid = (size - 1) >> 1;
  const int sizeP = DIR ? (size - 1 - mid) : (mid + 1);
  const int* lab = target + b * LL;
  const int lc = (l < 50) ? l : 50;
  const int tA = DIR ? (size - 2) : 1;
  constexpr int TS = DIR ? -1 : 1;
  const int bcap = DIR ? ((size - 5) >> 2) : 498;
  // packed-pair offsets (u32 index within record; +2 header)
  const int pbofs = 2 + (DIR ? CL50(50 - l) : CL50(l - 1));
  const int pcofs = 2 + (DIR ? CL50(49 - l) : CL50(l));
  const int payofs = 2 + (DIR ? CL50(51 - l) : CL50(l - 2));
  const float cmask = (l < 50) ? 1.f : 0.f;
  const int idx1 = ((l + 63) & 63) << 2;
  const float msk1 = (4 * l - 1 >= 0) ? 1.f : 0.f;
  const float msk2 = (4 * l - 2 >= 0) ? 1.f : 0.f;
  const float msk3 = (4 * l - 3 >= 0) ? 1.f : 0.f;
  const float msk4 = (4 * l - 4 >= 0) ? 1.f : 0.f;
  const float msk5 = (4 * l - 5 >= 0) ? 1.f : 0.f;
  const float msk6 = (4 * l - 6 >= 0) ? 1.f : 0.f;
  const float msk7 = (4 * l - 7 >= 0) ? 1.f : 0.f;
  // skip masks: fwd from lab ascending; bwd from reversed labels lab'[j]=lab[99-j]
  int i0, i1, i2, i3, i4, i5;
  if constexpr (DIR == 0) { i0 = 2*l+1; i1 = 2*l; i2 = 2*l-1; i3 = 2*l-2; i4 = 2*l-3; i5 = 2*l-4; }
  else { i0 = 98-2*l; i1 = 99-2*l; i2 = 100-2*l; i3 = 101-2*l; i4 = 102-2*l; i5 = 103-2*l; }
#define CLM(x) ((x) < 0 ? 0 : ((x) > 99 ? 99 : (x)))
  const int La = lab[CLM(i0)], Lb_ = lab[CLM(i1)], Lc = lab[CLM(i2)];
  const int Ld = lab[CLM(i3)], Le = lab[CLM(i4)], Lf = lab[CLM(i5)];
  const float cs_o3 = (La != Lb_) ? 1.f : 0.f;
  const float cs_o1 = (Lb_ != Lc) ? 1.f : 0.f;
  const float cs_h1 = (Lc != Ld) ? 1.f : 0.f;
  const float cs_h3 = (Ld != Le) ? 1.f : 0.f;
  const float cs_h5 = (Le != Lf) ? 1.f : 0.f;
  // init
  float o0 = 0.f, o1 = 0.f, o2 = 0.f, o3 = 0.f;
  float h1 = 0.f, h2 = 0.f, h3 = 0.f, h4 = 0.f, h5 = 0.f, h6 = 0.f, h7 = 0.f;
  int offs = 0;
  float msum;
  if constexpr (DIR == 0) {
    msum = recs_b[1];
    float q0i = blo(((const unsigned*)recs_b)[2]);   // q_lab[0]
    if (l == 0) { o0 = recs_b[0]; o1 = q0i; }
    if (l == 1) { h3 = q0i; h4 = recs_b[0]; }
    if (l == 2) { h7 = q0i; }
  } else {
    const float* recL = recs_b + (size_t)(size - 1) * RECW;
    msum = recL[1];
    const int Lbv = lablens[b];
    const int r0v = 200 - 2 * Lbv;   // rho of end state 2L; r0v+1 = rho of 2L-1
    auto gi = [&](int rho) -> float {
      if (rho != r0v && rho != r0v + 1) return 0.f;
      if ((rho & 1) == 0) return recL[0];
      int mm = 99 - ((rho - 1) >> 1);
      unsigned u = ((const unsigned*)recL)[2 + (mm >> 1)];
      return (mm & 1) ? bhi(u) : blo(u);
    };
    o0 = gi(4*l); o1 = gi(4*l+1); o2 = gi(4*l+2); o3 = gi(4*l+3);
    h1 = gi(4*l-1); h2 = gi(4*l-2); h3 = gi(4*l-3); h4 = gi(4*l-4);
    h5 = gi(4*l-5); h6 = gi(4*l-6); h7 = gi(4*l-7);
  }

  const int nb = (sizeP - 1) >> 2;
  DECLR(A); DECLR(B); DECLR(C);
  PREF(A, 0); PREF(B, 1);
  int blk = 0;
  for (; blk + 3 <= nb; blk += 3) {
    COMPA(A); PREF(C, blk + 2); FINL();
    COMPA(B); PREF(A, blk + 3); FINL();
    COMPA(C); PREF(B, blk + 4); FINL();
  }
  if (nb - blk >= 1) { COMPA(A); FINL(); }
  if (nb - blk >= 2) { COMPA(B); FINL(); }
  // tail (<=3 steps) + forward-only extra A-step
  {
    int rno1 = BPER(idx1, offs);
    int dtl = rno1 - offs;
    dtl = (dtl > 120) ? 120 : ((dtl < -300) ? -300 : dtl);
    for (int tau = 1 + 4 * nb; tau < sizeP; ++tau) {
      const float* rt = recs_b + (size_t)(DIR ? (size - 1 - tau) : tau) * RECW;
      float2 hh = *(const float2*)rt;
      float cx, cy;
      if constexpr (DIR == 0) {
        unsigned u = ((const unsigned*)rt)[2 + lc];   // pair lc (lc=50 -> zero pad)
        cx = blo(u); cy = bhi(u);
      } else {
        unsigned u = ((const unsigned*)rt)[2 + CL50(50 - l)];
        cx = bhi(u) * cmask; cy = blo(u) * cmask;
      }
      int rp = BPER(idx1, __float_as_int(o3));
      float p = ldexpf(__int_as_float(rp), dtl) * msk1;
      msum += hh.y;
      o3 = __builtin_fmaf(cs_o3, o1, o3 + o2) * cy;
      o2 = (o2 + o1) * hh.x;
      o1 = __builtin_fmaf(cs_o1, p, o1 + o0) * cx;
      o0 = (o0 + p) * hh.x;
    }
    if constexpr (DIR == 0) {   // alpha' = A * alpha_mid (absorbs leftover A^T)
      int rp = BPER(idx1, __float_as_int(o3));
      float p = ldexpf(__int_as_float(rp), dtl) * msk1;
      o3 = __builtin_fmaf(cs_o3, o1, o3 + o2);
      o2 = o2 + o1;
      o1 = __builtin_fmaf(cs_o1, p, o1 + o0);
      o0 = o0 + p;
    }
  }
  float* da = ws + SB_STATE + (size_t)(2 * b + DIR) * AREA;
  ((float4*)da)[l] = (float4){o0, o1, o2, o3};
  ((int*)da)[256 + l] = offs;
  if (l == 0) da[320] = msum;
}

// 128 threads = 2 independent waves per block: wave0 = fwd, wave1 = bwd (same b).
__global__ __launch_bounds__(128, 1) void k_alpha(const int* __restrict__ target,
                                                  const int* __restrict__ sizes,
                                                  const int* __restrict__ lablens,
                                                  float* __restrict__ ws) {
  __shared__ float ldsA[2 * 384];
  const int b = blockIdx.x;
  const int dirw = threadIdx.x >> 6;
  const int l = threadIdx.x & 63;
  float* exb = ldsA + dirw * 384;
  const int size = sizes[b];
  const float* recs_b = ws + REC_BASE + (size_t)b * TT * RECW;
  if (dirw == 0) run_chain<0>(target, lablens, recs_b, exb, size, b, l, ws);
  else           run_chain<1>(target, lablens, recs_b, exb, size, b, l, ws);
}

__global__ __launch_bounds__(64) void k_comb(float* __restrict__ ws) {
  const int b = blockIdx.x;
  const int l = threadIdx.x;
  const float* fa = ws + SB_STATE + (size_t)(2 * b) * AREA;
  const float* ba = fa + AREA;
  float4 av = ((const float4*)fa)[l];
  int eF = ((const int*)fa)[256 + l];
  float msF = fa[320], msB = ba[320];
  float pr0, pr1, pr2, pr3; int ex0, ex1, ex2, ex3, sb0, sb1, sb2, sb3;
#define CMP(k, AV, PR, EX, SBE) do {                                         \
    int s_ = 4 * l + (k);                                                    \
    int rho_ = 200 - s_;                                                     \
    int rc_ = (rho_ < 0) ? 0 : rho_;                                         \
    float g_ = ba[rc_];                                                      \
    int eB_ = ((const int*)ba)[256 + (rc_ >> 2)];                            \
    float p_ = (AV) * g_;                                                    \
    bool ok_ = (rho_ >= 0) && (p_ > 0.f);                                    \
    int eb_ = (int)((__float_as_uint(p_) >> 23) & 255u);                     \
    SBE = eF + eB_;                                                          \
    EX = ok_ ? (SBE + (eb_ ? eb_ - 127 : -140)) : (int)0xC0000000;           \
    PR = ok_ ? p_ : 0.f;                                                     \
  } while (0)
  CMP(0, av.x, pr0, ex0, sb0);
  CMP(1, av.y, pr1, ex1, sb1);
  CMP(2, av.z, pr2, ex2, sb2);
  CMP(3, av.w, pr3, ex3, sb3);
  int Em = ex0 > ex1 ? ex0 : ex1;
  Em = ex2 > Em ? ex2 : Em;
  Em = ex3 > Em ? ex3 : Em;
#pragma unroll
  for (int o = 32; o > 0; o >>= 1) {
    int t = __shfl_xor(Em, o, 64);
    Em = (t > Em) ? t : Em;
  }
  float v = 0.f;
#define ACC(PR, SBE) do { if (PR > 0.f) {                                    \
    int sh_ = SBE - Em; sh_ = sh_ < -300 ? -300 : (sh_ > 300 ? 300 : sh_);   \
    v += ldexpf(PR, sh_); } } while (0)
  ACC(pr0, sb0); ACC(pr1, sb1); ACC(pr2, sb2); ACC(pr3, sb3);
  float S = wave_sum64(v);
  if (l == 0) ws[b] = msF + msB + LN2 * ((float)Em + __builtin_log2f(S));
}

__global__ __launch_bounds__(64) void k_final(const float* __restrict__ ws, float* __restrict__ out) {
  float v = (threadIdx.x < BB) ? ws[threadIdx.x] : 0.0f;
  v = wave_sum64(v);
  if (threadIdx.x == 0) out[0] = -v;
}

extern "C" void kernel_launch(void* const* d_in, const int* in_sizes, int n_in,
                              void* d_out, int out_size, void* d_ws, size_t ws_size,
                              hipStream_t stream) {
  const float* acts  = (const float*)d_in[0];
  const int* target  = (const int*)d_in[1];
  const int* sizes   = (const int*)d_in[2];
  const int* lablens = (const int*)d_in[3];
  float* ws  = (float*)d_ws;
  float* out = (float*)d_out;
  const int nrec = TT * BB;
  k_gather<<<dim3(nrec / 4), dim3(256), 0, stream>>>(acts, target, ws);
  k_alpha<<<dim3(BB), dim3(128), 0, stream>>>(target, sizes, lablens, ws);
  k_comb<<<dim3(BB), dim3(64), 0, stream>>>(ws);
  k_final<<<dim3(1), dim3(64), 0, stream>>>(ws, out);
}